// Round 2
// baseline (799.367 us; speedup 1.0000x reference)
//
#include <hip/hip_runtime.h>
#include <math.h>

#define H 2048
#define S 2048
#define V 50257
#define NB5 1024   // blocks for out_w GEMV

// ws layout (float offsets). All inputs/outputs are FLOAT32 (per reference).
#define OFF_CAT    0        // 4096  : [embedded(2048) | attn_applied(2048)]
#define OFF_GH     4096     // 6144  : w_hh@h0 + b_hh
#define OFF_X      10240    // 2048  : relu(comb)
#define OFF_HNEW   12288    // 2048  : h_new fp32
#define OFF_LOGITS 14336    // 50432 : out logits fp32 (padded)
#define OFF_PART   64768    // 2048  : NB5 * (max, sumexp)
#define OFF_COLP   66816    // 32*2048 : colsum partials
// total: 132,352 floats = 529,408 bytes

__device__ inline float wave_reduce(float v) {
#pragma unroll
  for (int off = 32; off; off >>= 1) v += __shfl_xor(v, off, 64);
  return v;
}

__device__ inline float dot4(float4 a, float4 b) {
  return a.x * b.x + a.y * b.y + a.z * b.z + a.w * b.w;
}

// K1: (a) colsum partials of encoder_outputs, (b) gh = w_hh@h0 + b_hh,
//     (c) attn_weights = 1.0 output. Independent work, block-partitioned.
__global__ __launch_bounds__(256) void k1(const float* __restrict__ enc,
                                          const float* __restrict__ whh,
                                          const float* __restrict__ h0,
                                          const float* __restrict__ bhh,
                                          float* __restrict__ ws,
                                          float* __restrict__ out) {
  int blk = blockIdx.x, t = threadIdx.x;
  if (blk < 32) {
    // colsum: rows [blk*64, blk*64+64). Thread t covers cols [4t,4t+4) and
    // [1024+4t, 1024+4t+4).
    float4 acc0 = make_float4(0.f, 0.f, 0.f, 0.f);
    float4 acc1 = make_float4(0.f, 0.f, 0.f, 0.f);
    const float4* e4 = (const float4*)enc;  // 512 float4 per row
    int r0 = blk * 64;
    for (int r = 0; r < 64; ++r) {
      float4 a = e4[(size_t)(r0 + r) * 512 + t];
      float4 b = e4[(size_t)(r0 + r) * 512 + 256 + t];
      acc0.x += a.x; acc0.y += a.y; acc0.z += a.z; acc0.w += a.w;
      acc1.x += b.x; acc1.y += b.y; acc1.z += b.z; acc1.w += b.w;
    }
    float4* cp = (float4*)(ws + OFF_COLP + blk * 2048);
    cp[t] = acc0;
    cp[256 + t] = acc1;
  } else if (blk < 32 + 1536) {
    // gh GEMV: 6144 rows, wave per row
    int bg = blk - 32;
    int wave = t >> 6, lane = t & 63;
    int row = bg * 4 + wave;
    const float4* w4 = (const float4*)whh;  // 512 float4 per row
    const float4* h4 = (const float4*)h0;
    float acc = 0.f;
#pragma unroll
    for (int i = 0; i < 8; ++i) {
      int idx = i * 64 + lane;
      acc += dot4(w4[(size_t)row * 512 + idx], h4[idx]);
    }
    acc = wave_reduce(acc);
    if (lane == 0) ws[OFF_GH + row] = acc + bhh[row];
  } else {
    // attn_weights: softmax over singleton == 1.0 exactly
    int i = (blk - 1568) * 256 + t;  // 8 blocks -> 2048
    out[V + H + i] = 1.0f;
  }
}

// K2: build cat = [embedding row | colsum reduce]
__global__ __launch_bounds__(256) void k2(const int* __restrict__ tokp,
                                          const float* __restrict__ emb,
                                          float* __restrict__ ws) {
  int i = blockIdx.x * 256 + threadIdx.x;  // 0..4095
  if (i < H) {
    int tok = tokp[0];
    ws[OFF_CAT + i] = emb[(size_t)tok * H + i];
  } else {
    int j = i - H;
    float s = 0.f;
    for (int b = 0; b < 32; ++b) s += ws[OFF_COLP + b * 2048 + j];
    ws[OFF_CAT + H + j] = s;
  }
}

// K3: x = relu(comb_w @ cat + comb_b), wave per row (2048 rows x 4096 cols)
__global__ __launch_bounds__(256) void k3(const float* __restrict__ cw,
                                          const float* __restrict__ cb,
                                          float* __restrict__ ws) {
  int wave = threadIdx.x >> 6, lane = threadIdx.x & 63;
  int row = blockIdx.x * 4 + wave;
  const float4* w4 = (const float4*)cw;  // 1024 float4 per row
  const float4* c4 = (const float4*)(ws + OFF_CAT);
  float acc = 0.f;
#pragma unroll
  for (int i = 0; i < 16; ++i) {
    int idx = i * 64 + lane;
    acc += dot4(w4[(size_t)row * 1024 + idx], c4[idx]);
  }
  acc = wave_reduce(acc);
  if (lane == 0) {
    acc += cb[row];
    ws[OFF_X + row] = fmaxf(acc, 0.f);
  }
}

// K4: fused GRU step. Block j computes the 3 w_ih dots (rows j, H+j, 2H+j)
// against x, then the gate math -> h_new (fp32 in ws + out).
__global__ __launch_bounds__(256) void k4(const float* __restrict__ wih,
                                          const float* __restrict__ bih,
                                          const float* __restrict__ h0,
                                          float* __restrict__ ws,
                                          float* __restrict__ out) {
  int j = blockIdx.x;  // 0..2047
  int t = threadIdx.x;
  const float4* x4 = (const float4*)(ws + OFF_X);
  float4 a = x4[t * 2], b = x4[t * 2 + 1];  // cols 8t..8t+7
  const float4* w4 = (const float4*)wih;    // 512 float4 per row
  float acc[3];
#pragma unroll
  for (int g = 0; g < 3; ++g) {
    size_t row = (size_t)g * H + j;
    acc[g] = dot4(w4[row * 512 + t * 2], a) + dot4(w4[row * 512 + t * 2 + 1], b);
  }
  __shared__ float red[3][4];
  int wave = t >> 6, lane = t & 63;
#pragma unroll
  for (int g = 0; g < 3; ++g) {
    float v = wave_reduce(acc[g]);
    if (lane == 0) red[g][wave] = v;
  }
  __syncthreads();
  if (t == 0) {
    float gx[3];
#pragma unroll
    for (int g = 0; g < 3; ++g)
      gx[g] = red[g][0] + red[g][1] + red[g][2] + red[g][3] + bih[g * H + j];
    float ghr = ws[OFF_GH + j];
    float ghz = ws[OFF_GH + H + j];
    float ghn = ws[OFF_GH + 2 * H + j];
    float r = 1.f / (1.f + expf(-(gx[0] + ghr)));
    float z = 1.f / (1.f + expf(-(gx[1] + ghz)));
    float n = tanhf(gx[2] + r * ghn);
    float h = h0[j];
    float hn = (1.f - z) * n + z * h;
    ws[OFF_HNEW + j] = hn;
    out[V + j] = hn;
  }
}

// K5: logits = out_w @ h_new + out_b (V rows), wave per row grid-stride,
// with per-block online (max, sumexp) partials.
__global__ __launch_bounds__(256) void k5(const float* __restrict__ ow,
                                          const float* __restrict__ ob,
                                          float* __restrict__ ws) {
  int wave = threadIdx.x >> 6, lane = threadIdx.x & 63;
  int gw = blockIdx.x * 4 + wave;  // 0..4095
  float hreg[32];
  const float4* h4 = (const float4*)(ws + OFF_HNEW);
#pragma unroll
  for (int i = 0; i < 8; ++i) {
    float4 h = h4[i * 64 + lane];  // cols 4*(i*64+lane)..+3
    hreg[i * 4 + 0] = h.x; hreg[i * 4 + 1] = h.y;
    hreg[i * 4 + 2] = h.z; hreg[i * 4 + 3] = h.w;
  }
  float m = -INFINITY, s = 0.f;
  const float4* w4 = (const float4*)ow;  // 512 float4 per row
  for (int row = gw; row < V; row += 4096) {
    float acc = 0.f;
#pragma unroll
    for (int i = 0; i < 8; ++i) {
      float4 w = w4[(size_t)row * 512 + i * 64 + lane];
      acc += w.x * hreg[i * 4 + 0] + w.y * hreg[i * 4 + 1]
           + w.z * hreg[i * 4 + 2] + w.w * hreg[i * 4 + 3];
    }
    acc = wave_reduce(acc);  // all lanes hold the sum
    acc += ob[row];
    if (lane == 0) ws[OFF_LOGITS + row] = acc;
    if (acc > m) { s = s * __expf(m - acc) + 1.f; m = acc; }
    else s += __expf(acc - m);
  }
  __shared__ float sm[4], ss[4];
  if (lane == 0) { sm[wave] = m; ss[wave] = s; }
  __syncthreads();
  if (threadIdx.x == 0) {
    float M = fmaxf(fmaxf(sm[0], sm[1]), fmaxf(sm[2], sm[3]));
    float Sv = ss[0] * __expf(sm[0] - M) + ss[1] * __expf(sm[1] - M)
             + ss[2] * __expf(sm[2] - M) + ss[3] * __expf(sm[3] - M);
    ws[OFF_PART + 2 * blockIdx.x] = M;
    ws[OFF_PART + 2 * blockIdx.x + 1] = Sv;
  }
}

// K6: every block redundantly reduces the NB5 partials to (m, lse), then
// writes its slice of log_probs = logits - lse.
__global__ __launch_bounds__(256) void k6(const float* __restrict__ ws,
                                          float* __restrict__ out) {
  __shared__ float sm[256], ss[256];
  int t = threadIdx.x;
  float m = -INFINITY, s = 0.f;
  for (int p = t; p < NB5; p += 256) {
    float m2 = ws[OFF_PART + 2 * p], s2 = ws[OFF_PART + 2 * p + 1];
    float M = fmaxf(m, m2);
    s = s * __expf(m - M) + s2 * __expf(m2 - M);
    m = M;
  }
  sm[t] = m; ss[t] = s;
  __syncthreads();
  for (int off = 128; off; off >>= 1) {
    if (t < off) {
      float m2 = sm[t + off], s2 = ss[t + off];
      float M = fmaxf(sm[t], m2);
      ss[t] = ss[t] * __expf(sm[t] - M) + s2 * __expf(m2 - M);
      sm[t] = M;
    }
    __syncthreads();
  }
  float lse = sm[0] + logf(ss[0]);
  int i = blockIdx.x * 256 + t;
  if (i < V) out[i] = ws[OFF_LOGITS + i] - lse;
}

extern "C" void kernel_launch(void* const* d_in, const int* in_sizes, int n_in,
                              void* d_out, int out_size, void* d_ws, size_t ws_size,
                              hipStream_t stream) {
  const int* tok   = (const int*)d_in[0];
  const float* h0  = (const float*)d_in[1];
  const float* enc = (const float*)d_in[2];
  const float* emb = (const float*)d_in[3];
  // d_in[4] attn_w, d_in[5] attn_b: dead code (softmax over singleton == 1)
  const float* cw  = (const float*)d_in[6];
  const float* cb  = (const float*)d_in[7];
  const float* wih = (const float*)d_in[8];
  const float* whh = (const float*)d_in[9];
  const float* bih = (const float*)d_in[10];
  const float* bhh = (const float*)d_in[11];
  const float* ow  = (const float*)d_in[12];
  const float* ob  = (const float*)d_in[13];
  float* out = (float*)d_out;
  float* ws = (float*)d_ws;

  k1<<<1576, 256, 0, stream>>>(enc, whh, h0, bhh, ws, out);
  k2<<<16, 256, 0, stream>>>(tok, emb, ws);
  k3<<<512, 256, 0, stream>>>(cw, cb, ws);
  k4<<<2048, 256, 0, stream>>>(wih, bih, h0, ws, out);
  k5<<<NB5, 256, 0, stream>>>(ow, ob, ws);
  k6<<<197, 256, 0, stream>>>(ws, out);
}